// Round 2
// baseline (1201.579 us; speedup 1.0000x reference)
//
#include <hip/hip_runtime.h>
#include <hip/hip_bf16.h>
#include <stdint.h>

#define N_IN 250000
#define N_OUT 500000
#define INC 256
#define OUTC 128
#define KVOL 8
#define BN_EPS 1e-5f

typedef __bf16 bf16x8_t __attribute__((ext_vector_type(8)));
typedef __bf16 bf16x4_t __attribute__((ext_vector_type(4)));
typedef float f32x4_t __attribute__((ext_vector_type(4)));

__device__ __forceinline__ __bf16 f2bf(float x) {
  union { float f; uint32_t u; } v; v.f = x;
  uint32_t r = v.u + 0x7FFFu + ((v.u >> 16) & 1u);
  uint16_t h = (uint16_t)(r >> 16);
  union { uint16_t s; __bf16 b; } o; o.s = h;
  return o.b;
}

// Convert W[k][inc][outc] (fp32) -> Wt[k][outc][inc] (bf16), so that MFMA
// B-fragments (8 contiguous k-elements per lane) are contiguous 16B loads.
__global__ void wconv_kernel(const float* __restrict__ W, __bf16* __restrict__ Wt) {
  int f = blockIdx.x * blockDim.x + threadIdx.x;
  if (f >= KVOL * OUTC * INC) return;
  int i = f & (INC - 1);
  int o = (f >> 8) & (OUTC - 1);
  int k = f >> 15;
  Wt[f] = f2bf(W[(k * INC + i) * OUTC + o]);
}

#define TM 64          // input rows per block
#define LDS_STRIDE 264 // bf16 elems per LDS row: 256 + 8 pad (breaks bank conflicts)

// 512 threads = 8 waves. Wave w computes x_tile(64x256) @ W[w](256x128) via
// bf16 MFMA 16x16x32 and atomically scatters the 64x128 result rows to
// acc[out_idx[w][row]].
__global__ __launch_bounds__(512, 1) void gemm_scatter_kernel(
    const float* __restrict__ x, const __bf16* __restrict__ Wt,
    const int* __restrict__ out_idx, float* __restrict__ acc) {
  __shared__ __bf16 xs[TM * LDS_STRIDE];
  const int t = threadIdx.x;
  const int row0 = blockIdx.x * TM;

  // ---- stage x tile (64 x 256 fp32 -> bf16 LDS), zero-fill OOB rows ----
  #pragma unroll
  for (int i = 0; i < 8; ++i) {
    int f = t + i * 512;      // float4 index within tile (4096 total)
    int r = f >> 6;           // 64 float4 per row
    int c4 = f & 63;
    int grow = row0 + r;
    float4 v = make_float4(0.f, 0.f, 0.f, 0.f);
    if (grow < N_IN) v = ((const float4*)x)[(size_t)grow * 64 + c4];
    bf16x4_t bv;
    bv[0] = f2bf(v.x); bv[1] = f2bf(v.y); bv[2] = f2bf(v.z); bv[3] = f2bf(v.w);
    *(bf16x4_t*)&xs[r * LDS_STRIDE + c4 * 4] = bv;
  }
  __syncthreads();

  const int w  = t >> 6;   // wave id == kernel offset k
  const int l  = t & 63;
  const int lr = l & 15;   // fragment row/col index
  const int lg = l >> 4;   // 0..3 quarter-wave

  f32x4_t accr[4][8];
  #pragma unroll
  for (int m = 0; m < 4; ++m)
    #pragma unroll
    for (int n = 0; n < 8; ++n)
      accr[m][n] = (f32x4_t){0.f, 0.f, 0.f, 0.f};

  const __bf16* Wk = Wt + (size_t)w * OUTC * INC;  // [128][256] bf16

  #pragma unroll
  for (int s = 0; s < 8; ++s) {   // K in steps of 32
    bf16x8_t a[4], b[8];
    #pragma unroll
    for (int m = 0; m < 4; ++m) {
      int r = m * 16 + lr;
      a[m] = *(const bf16x8_t*)&xs[r * LDS_STRIDE + s * 32 + lg * 8];
    }
    #pragma unroll
    for (int n = 0; n < 8; ++n) {
      int col = n * 16 + lr;
      b[n] = *(const bf16x8_t*)&Wk[col * INC + s * 32 + lg * 8];
    }
    #pragma unroll
    for (int m = 0; m < 4; ++m)
      #pragma unroll
      for (int n = 0; n < 8; ++n)
        accr[m][n] = __builtin_amdgcn_mfma_f32_16x16x32_bf16(a[m], b[n], accr[m][n], 0, 0, 0);
  }

  // ---- scatter with atomics: C/D layout col = lr, row = lg*4 + reg (+16m) ----
  const int* oidx = out_idx + (size_t)w * N_IN;
  #pragma unroll
  for (int m = 0; m < 4; ++m) {
    int rbase = m * 16 + lg * 4;
    #pragma unroll
    for (int reg = 0; reg < 4; ++reg) {
      int grow = row0 + rbase + reg;
      if (grow < N_IN) {
        int dst = oidx[grow];
        float* ap = acc + (size_t)dst * OUTC;
        #pragma unroll
        for (int n = 0; n < 8; ++n)
          atomicAdd(&ap[n * 16 + lr], accr[m][n][reg]);
      }
    }
  }
}

// Column-wise sum and sum-of-squares over acc[N_OUT][128].
__global__ void stats_kernel(const float* __restrict__ acc, float* __restrict__ stats) {
  const int t = threadIdx.x;
  const int c4 = t & 31;   // which float4 column group
  const int ro = t >> 5;   // 0..7 row offset
  f32x4_t s = {0.f, 0.f, 0.f, 0.f}, q = {0.f, 0.f, 0.f, 0.f};
  for (int r = blockIdx.x * 8 + ro; r < N_OUT; r += gridDim.x * 8) {
    f32x4_t v = ((const f32x4_t*)acc)[(size_t)r * 32 + c4];
    s += v;
    q += v * v;
  }
  __shared__ float red[256][8];
  #pragma unroll
  for (int j = 0; j < 4; ++j) { red[t][j] = s[j]; red[t][4 + j] = q[j]; }
  __syncthreads();
  if (t < 32) {
    float S[4] = {0.f, 0.f, 0.f, 0.f}, Q[4] = {0.f, 0.f, 0.f, 0.f};
    for (int r2 = 0; r2 < 8; ++r2) {
      #pragma unroll
      for (int j = 0; j < 4; ++j) {
        S[j] += red[r2 * 32 + t][j];
        Q[j] += red[r2 * 32 + t][4 + j];
      }
    }
    #pragma unroll
    for (int j = 0; j < 4; ++j) {
      atomicAdd(&stats[t * 4 + j], S[j]);
      atomicAdd(&stats[128 + t * 4 + j], Q[j]);
    }
  }
}

// In-place BN normalize: y = (acc - mean) * rsqrt(var + eps) * gamma + beta
__global__ void norm_kernel(float* __restrict__ out, const float* __restrict__ stats,
                            const float* __restrict__ gamma, const float* __restrict__ beta) {
  const int t = threadIdx.x;
  const int c4 = t & 31;
  const int ro = t >> 5;
  const float inv_n = 1.0f / (float)N_OUT;
  float sc[4], sh[4];
  #pragma unroll
  for (int j = 0; j < 4; ++j) {
    int c = c4 * 4 + j;
    float mean = stats[c] * inv_n;
    float var  = stats[128 + c] * inv_n - mean * mean;
    float s = gamma[c] * rsqrtf(var + BN_EPS);
    sc[j] = s;
    sh[j] = beta[c] - mean * s;
  }
  for (int r = blockIdx.x * 8 + ro; r < N_OUT; r += gridDim.x * 8) {
    f32x4_t v = ((const f32x4_t*)out)[(size_t)r * 32 + c4];
    #pragma unroll
    for (int j = 0; j < 4; ++j) v[j] = v[j] * sc[j] + sh[j];
    ((f32x4_t*)out)[(size_t)r * 32 + c4] = v;
  }
}

extern "C" void kernel_launch(void* const* d_in, const int* in_sizes, int n_in,
                              void* d_out, int out_size, void* d_ws, size_t ws_size,
                              hipStream_t stream) {
  const float* x     = (const float*)d_in[0];
  const float* W     = (const float*)d_in[1];
  const float* gamma = (const float*)d_in[2];
  const float* beta  = (const float*)d_in[3];
  const int*   oidx  = (const int*)d_in[4];
  float* out = (float*)d_out;

  __bf16* Wt   = (__bf16*)d_ws;                                  // 512 KB
  float* stats = (float*)((char*)d_ws + (size_t)KVOL * OUTC * INC * 2);  // 1 KB

  hipMemsetAsync(d_out, 0, (size_t)N_OUT * OUTC * sizeof(float), stream);
  hipMemsetAsync(stats, 0, 256 * sizeof(float), stream);

  wconv_kernel<<<(KVOL * OUTC * INC + 255) / 256, 256, 0, stream>>>(W, Wt);
  gemm_scatter_kernel<<<(N_IN + TM - 1) / TM, 512, 0, stream>>>(x, Wt, oidx, out);
  stats_kernel<<<1024, 256, 0, stream>>>(out, stats);
  norm_kernel<<<2048, 256, 0, stream>>>(out, stats, gamma, beta);
}